// Round 2
// 123.572 us; speedup vs baseline: 1.0280x; 1.0280x over previous
//
#include <hip/hip_runtime.h>

// Firefly optimizer, round 9: 5 plain stream-ordered dispatches, no
// cooperative launch, no grid.sync.
//   aux_kernel  -- bf16 + sq of x0 (each row once).
//   fused_kernel x4 -- per step s: each block owns a 64-row i-tile, scans it
//     against ALL 4096 j of its species with MFMA fragments loaded DIRECTLY
//     from the global bf16 array (no LDS staging, no list ingestion, 1-deep
//     register prefetch). All attraction for the block's own rows lands in a
//     4KB LDS accumulator -> the block applies update s itself and writes
//     x_{s+1} fp32 + bf16 + sq (mix-scattered). Next dispatch reads them.
// Each of the 16384 rows per step is built EXACTLY once (R7 rebuilt rows 36x).
// Gate math bit-identical to R3..R8 (passed 5x): D = g_bf16 + (T-sqi)/2,
// hot <=> D > sqj/2; exact-fp32 slow path; il!=jl diagonal reject.

#define SPECIES 4
#define POP     4096
#define DIM     16
#define NSI     (SPECIES * POP)
#define T_CUT   10.0f

typedef __attribute__((ext_vector_type(8)))  short short8;    // 8 bf16
typedef __attribute__((ext_vector_type(16))) float floatx16;  // MFMA C/D

__device__ __forceinline__ unsigned short f2bf(float f) {
    unsigned u = __float_as_uint(f);
    u += 0x7FFFu + ((u >> 16) & 1u);
    return (unsigned short)(u >> 16);
}

// one row of 16 bf16 as two 16B stores (row = 32B, 32B-aligned)
__device__ __forceinline__ void store_row_bf16(unsigned short* dst,
                                               const float v[16]) {
    short8 a, b;
    #pragma unroll
    for (int d = 0; d < 8; ++d) {
        a[d] = (short)f2bf(v[d]);
        b[d] = (short)f2bf(v[d + 8]);
    }
    ((short8*)dst)[0] = a;
    ((short8*)dst)[1] = b;
}

__device__ __forceinline__ float cost16p(const float* __restrict__ v) {
    float sqv = 0.0f, cv = 0.0f;
    #pragma unroll
    for (int d = 0; d < 16; ++d) {
        sqv = fmaf(v[d], v[d], sqv);
        cv += cospif(2.0f * v[d]);
    }
    return 10.0f * DIM + sqv - 10.0f * cv;
}

// ---- aux: bf16 + sq of x0 (one thread per row) -----------------------------
__global__ __launch_bounds__(512) void aux_kernel(
        const float* __restrict__ x, unsigned short* __restrict__ xb,
        float* __restrict__ sq) {
    const int row = blockIdx.x * 512 + threadIdx.x;
    if (row >= NSI) return;
    const float* xr = x + (size_t)row * DIM;
    float v[16], s = 0.0f;
    #pragma unroll
    for (int d = 0; d < 16; ++d) {
        v[d] = xr[d];
        s = fmaf(v[d], v[d], s);
    }
    store_row_bf16(xb + (size_t)row * DIM, v);
    sq[row] = s;
}

// ---- fused scan + update for one step --------------------------------------
// grid 256 = (species, 64-row i-tile); 512 threads = 8 waves.
// wave w: i-subtile (w&1)*32, j-quarter (w>>1)*1024 (32 MFMA tiles).
__global__ __launch_bounds__(512) void fused_kernel(
        const float* __restrict__ xsf,            // exact fp32 x_s
        const unsigned short* __restrict__ xb16,  // bf16 x_s
        const float* __restrict__ sqg,            // |x_s|^2
        const float* __restrict__ nz,             // noise[s]
        float alpha, int mix, int last,
        float* __restrict__ xnf,                  // fp32 x_{s+1} (or d_out)
        unsigned short* __restrict__ xb16n,       // bf16 x_{s+1} (null if last)
        float* __restrict__ sqn) {                // sq  x_{s+1} (null if last)
    __shared__ float attr[64 * DIM];              // 4 KB

    const int tid = threadIdx.x;
    const int b   = blockIdx.x;                   // 0..255
    const int sp  = b >> 6;
    const int ib  = b & 63;
    const int sb  = sp * POP;
    const int i0  = ib * 64;                      // species-local i base

    attr[tid] = 0.0f;
    attr[tid + 512] = 0.0f;
    __syncthreads();

    const int lane = tid & 63, wave = tid >> 6;
    const int l31  = lane & 31, half = lane >> 5;
    const int itile = i0 + (wave & 1) * 32;       // species-local 32-row tile
    const int jq    = (wave >> 1) * 1024;         // species-local j-quarter
    const short8* xb = (const short8*)xb16;       // 2 x short8 per row

    const short8 afrag = xb[((sb + itile + l31) << 1) | half];

    floatx16 c;   // acc row r -> (r&3) + 8*(r>>2) + 4*half
    {
        const float* sp_ = sqg + sb + itile + 4 * half;
        #pragma unroll
        for (int bq = 0; bq < 4; ++bq)
            #pragma unroll
            for (int t2 = 0; t2 < 4; ++t2)
                c[4 * bq + t2] = 0.5f * (T_CUT - sp_[8 * bq + t2]);
    }

    // 32 MFMA tiles, fragments straight from global bf16 (L2-hot),
    // 1-deep register prefetch.
    short8 bf_n = xb[((sb + jq + l31) << 1) | half];
    float  sq_n = sqg[sb + jq + l31];
    for (int t = 0; t < 32; ++t) {
        const int j0 = jq + t * 32;
        const short8 bfrag = bf_n;
        const float  hsqj  = 0.5f * sq_n;
        if (t + 1 < 32) {
            bf_n = xb[((sb + j0 + 32 + l31) << 1) | half];
            sq_n = sqg[sb + j0 + 32 + l31];
        }
        floatx16 d = __builtin_amdgcn_mfma_f32_32x32x16_bf16(afrag, bfrag, c,
                                                             0, 0, 0);
        float m0 = fmaxf(fmaxf(d[0], d[1]),   fmaxf(d[2], d[3]));
        float m1 = fmaxf(fmaxf(d[4], d[5]),   fmaxf(d[6], d[7]));
        float m2 = fmaxf(fmaxf(d[8], d[9]),   fmaxf(d[10], d[11]));
        float m3 = fmaxf(fmaxf(d[12], d[13]), fmaxf(d[14], d[15]));
        float m  = fmaxf(fmaxf(m0, m1), fmaxf(m2, m3));

        if (__any(m > hsqj)) {
            const int jl = j0 + l31;              // species-local
            #pragma unroll 1
            for (int r = 0; r < 16; ++r) {
                if (d[r] > hsqj) {
                    const int il = itile + (r & 3) + 8 * (r >> 2) + 4 * half;
                    if (il != jl) {               // diagonal: integer reject
                        const float* xi = xsf + (size_t)(sb + il) * DIM;
                        const float* xj = xsf + (size_t)(sb + jl) * DIM;
                        float dot = 0.0f;
                        #pragma unroll
                        for (int dd = 0; dd < 16; ++dd)
                            dot = fmaf(xi[dd], xj[dd], dot);
                        float d2 = fmaxf(fmaf(-2.0f, dot,
                                sqg[sb + il] + sqg[sb + jl]), 0.0f);
                        if (d2 < T_CUT && cost16p(xi) > cost16p(xj)) {
                            float w = 2.0f * expf(-d2);
                            #pragma unroll
                            for (int dd = 0; dd < 16; ++dd)
                                atomicAdd(&attr[(il - i0) * DIM + dd],
                                          w * (xj[dd] - xi[dd]));
                        }
                    }
                }
            }
        }
    }
    __syncthreads();

    // update: one thread per owned row; write x_{s+1} (mix-scattered)
    if (tid < 64) {
        const int i = i0 + tid;
        const int grow = sb + i;
        const float* xr = xsf + (size_t)grow * DIM;
        const float* nr = nz + (size_t)grow * DIM;
        float v[16], sqv = 0.0f;
        #pragma unroll
        for (int d = 0; d < 16; ++d) {
            float xn = (xr[d] + attr[tid * DIM + d])
                     + alpha * (nr[d] - 0.5f) * 8.0f;
            xn = fminf(fmaxf(xn, -4.0f), 4.0f);
            v[d] = xn;
            sqv = fmaf(xn, xn, sqv);
        }
        const int s_out = (mix && i >= POP / 2) ? ((sp + 1) & (SPECIES - 1))
                                                : sp;
        const size_t go = (size_t)s_out * POP + i;
        float* o = xnf + go * DIM;
        #pragma unroll
        for (int d = 0; d < 16; ++d) o[d] = v[d];
        if (!last) {
            store_row_bf16(xb16n + go * DIM, v);
            sqn[go] = sqv;
        }
    }
}

extern "C" void kernel_launch(void* const* d_in, const int* in_sizes, int n_in,
                              void* d_out, int out_size, void* d_ws, size_t ws_size,
                              hipStream_t stream) {
    const float* x0    = (const float*)d_in[0];
    const float* noise = (const float*)d_in[1];
    const int steps = in_sizes[1] / in_sizes[0];            // = 4

    float* xfA = (float*)d_ws;                              // NSI*16 f32
    float* xfB = xfA + (size_t)NSI * DIM;                   // NSI*16 f32
    float* sqA = xfB + (size_t)NSI * DIM;                   // NSI f32
    float* sqB = sqA + NSI;                                 // NSI f32
    unsigned short* xbA = (unsigned short*)(sqB + NSI);     // NSI*16 bf16
    unsigned short* xbB = xbA + (size_t)NSI * DIM;          // NSI*16 bf16

    aux_kernel<<<NSI / 512, 512, 0, stream>>>(x0, xbA, sqA);

    const float* xs = x0;
    const unsigned short* xbc = xbA;
    const float* sqc = sqA;
    float alpha = 0.1f;
    for (int s = 0; s < steps; ++s) {
        const int last = (s + 1 == steps);
        const int mixs = (s % 25 == 0) ? 1 : 0;
        float*          xout = last ? (float*)d_out : ((s & 1) ? xfB : xfA);
        unsigned short* xbn  = (s & 1) ? xbA : xbB;
        float*          sqn  = (s & 1) ? sqA : sqB;
        fused_kernel<<<SPECIES * (POP / 64), 512, 0, stream>>>(
            xs, xbc, sqc, noise + (size_t)s * NSI * DIM,
            alpha, mixs, last,
            xout, last ? nullptr : xbn, last ? nullptr : sqn);
        xs = xout; xbc = xbn; sqc = sqn;
        alpha *= 0.995f;
    }
}